// Round 15
// baseline (62.544 us; speedup 1.0000x reference)
//
#include <hip/hip_runtime.h>
#include <hip/hip_bf16.h>
#include <hip/hip_fp16.h>

// Problem constants (fixed by setup_inputs)
#define CIN      8
#define HH       100
#define WW       152
#define HWSZ     (HH * WW)          // 15200
#define OHGT     200
#define OWID     304
#define PPI      419                 // params per instance: 169 body + 169 edge + 81 fused
#define OUT_PER_INST (OHGT * OWID)   // 60800

#define RSTRIP   10                  // interior logit rows per block (100 = 10*10)
#define TROWS    11                  // 10 interior + 1 halo
#define NSTRIPS  10
#define NQUAD    (TROWS * 38)        // 418 quads of 4 px per block
#define P2ITEMS  (3 * RSTRIP * 76)   // 2280 upsample items per block

// Per-instance param layout (row of 419 floats):
//  body:  w1[8][10]@0  w2[8][8]@80  w3[8]@144  b1[8]@152 b2[8]@160 b3@168
//  edge:  same +169
//  fused: wf1[8][8]@338 wf2[8]@402 bf1[8]@410 bf2@418

typedef float vf4 __attribute__((ext_vector_type(4)));

// R8-proven: vector w*x+a (fuses+packs). R9: scalarized fmaf WORSE.
// R13: LDS-staged weights WORSE (SGPR weights are free operands).
__device__ __forceinline__ vf4 fma4(float w, vf4 x, vf4 a) { return w * x + a; }
__device__ __forceinline__ vf4 relu4(vf4 x) {
    vf4 r; r.x = fmaxf(x.x, 0.f); r.y = fmaxf(x.y, 0.f);
    r.z = fmaxf(x.z, 0.f); r.w = fmaxf(x.w, 0.f); return r;
}

// ------------------------------------------------------------------------
// Fused kernel, 256 threads. Block = (instance n, 10-row strip s).
// R15 change: TWO quads (A,B) per thread with INNER-LOOP interleaving --
// each scalar weight load feeds two back-to-back fma4 (A then B), halving
// the per-wave s_load stream per unit of FLOP (the hypothesized correlated
// scalar-stall source). 10-row strip also halves halo recompute (20%->10%).
// Phase 2: closed-form x2 aligned_bilinear + sigmoid, NT vf4 stores.
// ------------------------------------------------------------------------
__global__ __launch_bounds__(256) void dmh_fused7_kernel(
    const float* __restrict__ fbody,      // [2][8][H][W]
    const float* __restrict__ fedge,      // [2][8][H][W]
    const float* __restrict__ params,     // [n_inst][419]
    const float* __restrict__ locs,       // [n_inst][2]
    const float* __restrict__ soi_tab,    // [5]
    const int*   __restrict__ im_inds,    // [n_inst]
    const int*   __restrict__ fpn_levels, // [n_inst]
    float* __restrict__ out,              // [3][n_inst][200][304]
    int n_inst)
{
    const int s   = blockIdx.x;
    const int n   = blockIdx.y;
    const int tid = threadIdx.x;
    const int r0  = RSTRIP * s;

    __shared__ float slog[3][TROWS][WW];  // 20.1 KB

    const float* __restrict__ p = params + (size_t)n * PPI;
    const int   im      = im_inds[n];
    const float inv_soi = 1.0f / soi_tab[fpn_levels[n]];
    const float sx = (locs[2 * n]     - 4.0f) * inv_soi;
    const float sy = (locs[2 * n + 1] - 4.0f) * inv_soi;
    const float k8 = 8.0f * inv_soi;

    const float* __restrict__ fb_base = fbody + (size_t)im * CIN * HWSZ;
    const float* __restrict__ fe_base = fedge + (size_t)im * CIN * HWSZ;

    // ---------------- Phase 1: dual-quad (8 px) dynamic MLPs -> LDS ----------------
    // Quads 0..417; thread t (< 228) owns quad t, and quad t+228 if t < 190.
    if (tid < 228) {
        const bool hasB = (tid < NQUAD - 228);      // 190 threads carry a B quad
        const int qA = tid;
        const int qB = hasB ? tid + 228 : tid;      // inactive B duplicates A (stores gated)

        const int rlA = qA / 38, cA = (qA - rlA * 38) * 4;
        const int rlB = qB / 38, cB = (qB - rlB * 38) * 4;
        const int rA = min(r0 + rlA, HH - 1);
        const int rB = min(r0 + rlB, HH - 1);
        const int pxA = rA * WW + cA;
        const int pxB = rB * WW + cB;

        const float dxA0 = sx - (float)cA * k8;
        const float dxB0 = sx - (float)cB * k8;
        const vf4 dxA = { dxA0, dxA0 - k8, dxA0 - 2.f * k8, dxA0 - 3.f * k8 };
        const vf4 dxB = { dxB0, dxB0 - k8, dxB0 - 2.f * k8, dxB0 - 3.f * k8 };
        const float dyAv = sy - (float)rA * k8;
        const float dyBv = sy - (float)rB * k8;
        const vf4 dyA = { dyAv, dyAv, dyAv, dyAv };
        const vf4 dyB = { dyBv, dyBv, dyBv, dyBv };

        // ---- all feature loads issued up front (compiler may reschedule) ----
        vf4 fA[8], fB[8], gA[8], gB[8];
        #pragma unroll
        for (int k = 0; k < 8; ++k) {
            fA[k] = *(const vf4*)(fb_base + k * HWSZ + pxA);
            fB[k] = *(const vf4*)(fb_base + k * HWSZ + pxB);
        }
        #pragma unroll
        for (int k = 0; k < 8; ++k) {
            gA[k] = *(const vf4*)(fe_base + k * HWSZ + pxA);
            gB[k] = *(const vf4*)(fe_base + k * HWSZ + pxB);
        }

        vf4 h1A[8], h1B[8];

        // ---- body L1 (each weight: 2 back-to-back uses) ----
        #pragma unroll
        for (int o = 0; o < 8; ++o) {
            const float b = p[152 + o];
            vf4 aA = b, aB = b;
            const float w0 = p[o * 10 + 0], w1 = p[o * 10 + 1];
            aA = fma4(w0, dxA, aA); aB = fma4(w0, dxB, aB);
            aA = fma4(w1, dyA, aA); aB = fma4(w1, dyB, aB);
            #pragma unroll
            for (int k = 0; k < 8; ++k) {
                const float w = p[o * 10 + 2 + k];
                aA = fma4(w, fA[k], aA); aB = fma4(w, fB[k], aB);
            }
            h1A[o] = relu4(aA); h1B[o] = relu4(aB);
        }
        // ---- body L2 ----
        vf4 h2bA[8], h2bB[8];                 // later hs = h2b + he, in place
        #pragma unroll
        for (int o = 0; o < 8; ++o) {
            const float b = p[160 + o];
            vf4 aA = b, aB = b;
            #pragma unroll
            for (int k = 0; k < 8; ++k) {
                const float w = p[80 + o * 8 + k];
                aA = fma4(w, h1A[k], aA); aB = fma4(w, h1B[k], aB);
            }
            h2bA[o] = relu4(aA); h2bB[o] = relu4(aB);
        }
        vf4 lbA = p[168], lbB = p[168];
        #pragma unroll
        for (int k = 0; k < 8; ++k) {
            const float w = p[144 + k];
            lbA = fma4(w, h2bA[k], lbA); lbB = fma4(w, h2bB[k], lbB);
        }

        // ---- edge L1 (h1 regs reused) ----
        #pragma unroll
        for (int o = 0; o < 8; ++o) {
            const float b = p[169 + 152 + o];
            vf4 aA = b, aB = b;
            const float w0 = p[169 + o * 10 + 0], w1 = p[169 + o * 10 + 1];
            aA = fma4(w0, dxA, aA); aB = fma4(w0, dxB, aB);
            aA = fma4(w1, dyA, aA); aB = fma4(w1, dyB, aB);
            #pragma unroll
            for (int k = 0; k < 8; ++k) {
                const float w = p[169 + o * 10 + 2 + k];
                aA = fma4(w, gA[k], aA); aB = fma4(w, gB[k], aB);
            }
            h1A[o] = relu4(aA); h1B[o] = relu4(aB);
        }
        // ---- edge L2 (he never arrayed; hs formed in place) ----
        vf4 leA = p[169 + 168], leB = p[169 + 168];
        #pragma unroll
        for (int o = 0; o < 8; ++o) {
            const float b = p[169 + 160 + o];
            vf4 aA = b, aB = b;
            #pragma unroll
            for (int k = 0; k < 8; ++k) {
                const float w = p[169 + 80 + o * 8 + k];
                aA = fma4(w, h1A[k], aA); aB = fma4(w, h1B[k], aB);
            }
            const vf4 heA = relu4(aA), heB = relu4(aB);
            const float w3 = p[169 + 144 + o];
            leA = fma4(w3, heA, leA); leB = fma4(w3, heB, leB);
            h2bA[o] = h2bA[o] + heA; h2bB[o] = h2bB[o] + heB;
        }

        // ---- fused head on hs ----
        vf4 hfA[8], hfB[8];
        #pragma unroll
        for (int o = 0; o < 8; ++o) {
            const float b = p[410 + o];
            vf4 aA = b, aB = b;
            #pragma unroll
            for (int k = 0; k < 8; ++k) {
                const float w = p[338 + o * 8 + k];
                aA = fma4(w, h2bA[k], aA); aB = fma4(w, h2bB[k], aB);
            }
            hfA[o] = relu4(aA); hfB[o] = relu4(aB);
        }
        vf4 lfA = p[418], lfB = p[418];
        #pragma unroll
        for (int k = 0; k < 8; ++k) {
            const float w = p[402 + k];
            lfA = fma4(w, hfA[k], lfA); lfB = fma4(w, hfB[k], lfB);
        }

        *(vf4*)&slog[0][rlA][cA] = lbA;
        *(vf4*)&slog[1][rlA][cA] = leA;
        *(vf4*)&slog[2][rlA][cA] = lfA;
        if (hasB) {
            *(vf4*)&slog[0][rlB][cB] = lbB;
            *(vf4*)&slog[1][rlB][cB] = leB;
            *(vf4*)&slog[2][rlB][cB] = lfB;
        }
    }
    __syncthreads();

    // ------- Phase 2: x2 aligned_bilinear + sigmoid + NT vf4 stores -------
    // item = (h, rr, q): output rows y=2r+1 (A), y=2r+2 (B), cols 4q..4q+3.
    //   x=4q: (L[2q-1]+L[2q])/2   x=4q+1: L[2q]
    //   x=4q+2: (L[2q]+L[2q+1])/2 x=4q+3: L[2q+1]  (cols clamped to [0,151])
    // Row B averages LDS rows rr,rr+1 (halo pre-clamped). y=0==y=1 at r==0;
    // row B dropped at r==99.
    for (int it = tid; it < P2ITEMS; it += 256) {
        const int h   = it / (RSTRIP * 76);
        const int rem = it - h * (RSTRIP * 76);
        const int rr  = rem / 76;
        const int q   = rem - rr * 76;
        const int r   = r0 + rr;

        const int cm = max(2 * q - 1, 0);
        const int c0 = 2 * q;
        const int cp = min(2 * q + 1, WW - 1);

        const float Lm0 = slog[h][rr][cm],     L00 = slog[h][rr][c0],     Lp0 = slog[h][rr][cp];
        const float Lm1 = slog[h][rr + 1][cm], L01 = slog[h][rr + 1][c0], Lp1 = slog[h][rr + 1][cp];

        const float a0 = 0.5f * (Lm0 + L00);
        const float a1 = L00;
        const float a2 = 0.5f * (L00 + Lp0);
        const float a3 = Lp0;
        const float m  = 0.5f * (Lm0 + Lm1);
        const float z  = 0.5f * (L00 + L01);
        const float pz = 0.5f * (Lp0 + Lp1);
        const float b0 = 0.5f * (m + z);
        const float b1 = z;
        const float b2 = 0.5f * (z + pz);
        const float b3 = pz;

        vf4 A, B;
        A.x = 1.0f / (1.0f + __expf(-a0));
        A.y = 1.0f / (1.0f + __expf(-a1));
        A.z = 1.0f / (1.0f + __expf(-a2));
        A.w = 1.0f / (1.0f + __expf(-a3));
        B.x = 1.0f / (1.0f + __expf(-b0));
        B.y = 1.0f / (1.0f + __expf(-b1));
        B.z = 1.0f / (1.0f + __expf(-b2));
        B.w = 1.0f / (1.0f + __expf(-b3));

        float* __restrict__ O = out + ((size_t)h * n_inst + n) * OUT_PER_INST;
        const int xq = 4 * q;
        __builtin_nontemporal_store(A, (vf4*)(O + (size_t)(2 * r + 1) * OWID + xq)); // y=2r+1
        if (r == 0)
            __builtin_nontemporal_store(A, (vf4*)(O + xq));                           // y=0 (==y=1)
        if (r < HH - 1)
            __builtin_nontemporal_store(B, (vf4*)(O + (size_t)(2 * r + 2) * OWID + xq)); // y=2r+2
    }
}

extern "C" void kernel_launch(void* const* d_in, const int* in_sizes, int n_in,
                              void* d_out, int out_size, void* d_ws, size_t ws_size,
                              hipStream_t stream) {
    const float* fbody   = (const float*)d_in[0];
    const float* fedge   = (const float*)d_in[1];
    const float* params  = (const float*)d_in[2];
    const float* locs    = (const float*)d_in[3];
    const float* soi     = (const float*)d_in[4];
    const int*   im_inds = (const int*)d_in[5];
    const int*   fpn     = (const int*)d_in[6];
    // d_in[7] = mask_feat_stride (always 8; factor=2 baked into the closed form)

    const int n_inst = in_sizes[5];  // 128

    dim3 grid(NSTRIPS, n_inst);
    dmh_fused7_kernel<<<grid, dim3(256), 0, stream>>>(
        fbody, fedge, params, locs, soi, im_inds, fpn,
        (float*)d_out, n_inst);
}

// Round 16
// 42.151 us; speedup vs baseline: 1.4838x; 1.4838x over previous
//
#include <hip/hip_runtime.h>
#include <hip/hip_bf16.h>
#include <hip/hip_fp16.h>

// Problem constants (fixed by setup_inputs)
#define CIN      8
#define HH       100
#define WW       152
#define HWSZ     (HH * WW)          // 15200
#define OHGT     200
#define OWID     304
#define PPI      419                 // params per instance: 169 body + 169 edge + 81 fused
#define OUT_PER_INST (OHGT * OWID)   // 60800

#define RSTRIP   10                  // interior logit rows per block (100 = 10*10)
#define TROWS    11                  // 10 interior + 1 halo
#define NSTRIPS  10
#define NQUAD    (TROWS * 38)        // 418 quads of 4 px per block
#define P2ITEMS  (3 * RSTRIP * 76)   // 2280 upsample items per block

// Per-instance param layout (row of 419 floats):
//  body:  w1[8][10]@0  w2[8][8]@80  w3[8]@144  b1[8]@152 b2[8]@160 b3@168
//  edge:  same +169
//  fused: wf1[8][8]@338 wf2[8]@402 bf1[8]@410 bf2@418

typedef float vf4 __attribute__((ext_vector_type(4)));

// R8-proven: vector w*x+a (fuses+packs). R9: scalarized fmaf WORSE.
// R13: LDS-staged weights WORSE. R15: INTERLEAVED dual-quad spills (VGPR=68,
// 6GB scratch fetch) -- quads must be SEQUENTIAL, separated by a barrier.
__device__ __forceinline__ vf4 fma4(float w, vf4 x, vf4 a) { return w * x + a; }
__device__ __forceinline__ vf4 relu4(vf4 x) {
    vf4 r; r.x = fmaxf(x.x, 0.f); r.y = fmaxf(x.y, 0.f);
    r.z = fmaxf(x.z, 0.f); r.w = fmaxf(x.w, 0.f); return r;
}

// ------------------------------------------------------------------------
// Fused kernel, 256 threads. Block = (instance n, 10-row strip s).
// R16: two SEQUENTIAL quad passes (pass A: 256 quads, 100% utilization;
// pass B: 162 quads) with a barrier between to keep register pressure at
// single-quad level. 10-row strip halves halo recompute (20%->10%) and
// halves block count vs R11. Body per quad = untouched R11/R14 code.
// Phase 2: closed-form x2 aligned_bilinear + sigmoid, NT vf4 stores.
// ------------------------------------------------------------------------
__global__ __launch_bounds__(256) void dmh_fused8_kernel(
    const float* __restrict__ fbody,      // [2][8][H][W]
    const float* __restrict__ fedge,      // [2][8][H][W]
    const float* __restrict__ params,     // [n_inst][419]
    const float* __restrict__ locs,       // [n_inst][2]
    const float* __restrict__ soi_tab,    // [5]
    const int*   __restrict__ im_inds,    // [n_inst]
    const int*   __restrict__ fpn_levels, // [n_inst]
    float* __restrict__ out,              // [3][n_inst][200][304]
    int n_inst)
{
    const int s   = blockIdx.x;
    const int n   = blockIdx.y;
    const int tid = threadIdx.x;
    const int r0  = RSTRIP * s;

    __shared__ float slog[3][TROWS][WW];  // 20.1 KB

    const float* __restrict__ p = params + (size_t)n * PPI;
    const int   im      = im_inds[n];
    const float inv_soi = 1.0f / soi_tab[fpn_levels[n]];
    const float sx = (locs[2 * n]     - 4.0f) * inv_soi;
    const float sy = (locs[2 * n + 1] - 4.0f) * inv_soi;
    const float k8 = 8.0f * inv_soi;

    const float* __restrict__ fb_base = fbody + (size_t)im * CIN * HWSZ;
    const float* __restrict__ fe_base = fedge + (size_t)im * CIN * HWSZ;

    // ---- one 4-px quad of the dynamic MLPs -> LDS (R11 body, verbatim) ----
    auto do_quad = [&](int quad) {
        const int rl = quad / 38;
        const int c  = (quad - rl * 38) * 4;  // 0,4,...,148
        const int r  = min(r0 + rl, HH - 1);  // halo row clamps (edge-pad)
        const int px = r * WW + c;

        const float dx0 = sx - (float)c * k8;
        const vf4 dx = { dx0, dx0 - k8, dx0 - 2.f * k8, dx0 - 3.f * k8 };
        const float dyv = sy - (float)r * k8;
        const vf4 dy = { dyv, dyv, dyv, dyv };

        const float* __restrict__ fb = fb_base + px;
        const float* __restrict__ fe = fe_base + px;

        vf4 inb[10], ine[8];
        inb[0] = dx; inb[1] = dy;
        #pragma unroll
        for (int k = 0; k < 8; ++k)
            inb[k + 2] = *(const vf4*)(fb + k * HWSZ);   // 16B coalesced
        #pragma unroll
        for (int k = 0; k < 8; ++k)
            ine[k] = *(const vf4*)(fe + k * HWSZ);

        vf4 h1[8];

        // body head
        #pragma unroll
        for (int o = 0; o < 8; ++o) {
            vf4 a = p[152 + o];
            #pragma unroll
            for (int k = 0; k < 10; ++k) a = fma4(p[o * 10 + k], inb[k], a);
            h1[o] = relu4(a);
        }
        vf4 h2b[8];                       // later becomes hs = h2b + h2e
        #pragma unroll
        for (int o = 0; o < 8; ++o) {
            vf4 a = p[160 + o];
            #pragma unroll
            for (int k = 0; k < 8; ++k) a = fma4(p[80 + o * 8 + k], h1[k], a);
            h2b[o] = relu4(a);
        }
        vf4 lb = p[168];
        #pragma unroll
        for (int k = 0; k < 8; ++k) lb = fma4(p[144 + k], h2b[k], lb);

        // edge head (h1 regs reused; h2e never materialized as array)
        #pragma unroll
        for (int o = 0; o < 8; ++o) {
            vf4 a = p[169 + 152 + o];
            a = fma4(p[169 + o * 10 + 0], dx, a);
            a = fma4(p[169 + o * 10 + 1], dy, a);
            #pragma unroll
            for (int k = 0; k < 8; ++k) a = fma4(p[169 + o * 10 + 2 + k], ine[k], a);
            h1[o] = relu4(a);
        }
        vf4 le = p[169 + 168];
        #pragma unroll
        for (int o = 0; o < 8; ++o) {
            vf4 a = p[169 + 160 + o];
            #pragma unroll
            for (int k = 0; k < 8; ++k) a = fma4(p[169 + 80 + o * 8 + k], h1[k], a);
            const vf4 he = relu4(a);
            le = fma4(p[169 + 144 + o], he, le);   // incremental edge logit
            h2b[o] = h2b[o] + he;                  // hs in place
        }

        // fused head on hs
        vf4 hf[8];
        #pragma unroll
        for (int o = 0; o < 8; ++o) {
            vf4 a = p[410 + o];
            #pragma unroll
            for (int k = 0; k < 8; ++k) a = fma4(p[338 + o * 8 + k], h2b[k], a);
            hf[o] = relu4(a);
        }
        vf4 lf = p[418];
        #pragma unroll
        for (int k = 0; k < 8; ++k) lf = fma4(p[402 + k], hf[k], lf);

        *(vf4*)&slog[0][rl][c] = lb;   // 16B-aligned LDS writes (c%4==0)
        *(vf4*)&slog[1][rl][c] = le;
        *(vf4*)&slog[2][rl][c] = lf;
    };

    // ---------------- Phase 1: two sequential passes ----------------
    do_quad(tid);                          // quads 0..255, all threads active
    __syncthreads();                       // register-pressure firewall
    if (tid < NQUAD - 256)                 // quads 256..417 (162 threads)
        do_quad(256 + tid);
    __syncthreads();

    // ------- Phase 2: x2 aligned_bilinear + sigmoid + NT vf4 stores -------
    // item = (h, rr, q): output rows y=2r+1 (A), y=2r+2 (B), cols 4q..4q+3.
    //   x=4q: (L[2q-1]+L[2q])/2   x=4q+1: L[2q]
    //   x=4q+2: (L[2q]+L[2q+1])/2 x=4q+3: L[2q+1]  (cols clamped to [0,151])
    // Row B averages LDS rows rr,rr+1 (halo pre-clamped). y=0==y=1 at r==0;
    // row B dropped at r==99.
    for (int it = tid; it < P2ITEMS; it += 256) {
        const int h   = it / (RSTRIP * 76);
        const int rem = it - h * (RSTRIP * 76);
        const int rr  = rem / 76;
        const int q   = rem - rr * 76;
        const int r   = r0 + rr;

        const int cm = max(2 * q - 1, 0);
        const int c0 = 2 * q;
        const int cp = min(2 * q + 1, WW - 1);

        const float Lm0 = slog[h][rr][cm],     L00 = slog[h][rr][c0],     Lp0 = slog[h][rr][cp];
        const float Lm1 = slog[h][rr + 1][cm], L01 = slog[h][rr + 1][c0], Lp1 = slog[h][rr + 1][cp];

        const float a0 = 0.5f * (Lm0 + L00);
        const float a1 = L00;
        const float a2 = 0.5f * (L00 + Lp0);
        const float a3 = Lp0;
        const float m  = 0.5f * (Lm0 + Lm1);
        const float z  = 0.5f * (L00 + L01);
        const float pz = 0.5f * (Lp0 + Lp1);
        const float b0 = 0.5f * (m + z);
        const float b1 = z;
        const float b2 = 0.5f * (z + pz);
        const float b3 = pz;

        vf4 A, B;
        A.x = 1.0f / (1.0f + __expf(-a0));
        A.y = 1.0f / (1.0f + __expf(-a1));
        A.z = 1.0f / (1.0f + __expf(-a2));
        A.w = 1.0f / (1.0f + __expf(-a3));
        B.x = 1.0f / (1.0f + __expf(-b0));
        B.y = 1.0f / (1.0f + __expf(-b1));
        B.z = 1.0f / (1.0f + __expf(-b2));
        B.w = 1.0f / (1.0f + __expf(-b3));

        float* __restrict__ O = out + ((size_t)h * n_inst + n) * OUT_PER_INST;
        const int xq = 4 * q;
        __builtin_nontemporal_store(A, (vf4*)(O + (size_t)(2 * r + 1) * OWID + xq)); // y=2r+1
        if (r == 0)
            __builtin_nontemporal_store(A, (vf4*)(O + xq));                           // y=0 (==y=1)
        if (r < HH - 1)
            __builtin_nontemporal_store(B, (vf4*)(O + (size_t)(2 * r + 2) * OWID + xq)); // y=2r+2
    }
}

extern "C" void kernel_launch(void* const* d_in, const int* in_sizes, int n_in,
                              void* d_out, int out_size, void* d_ws, size_t ws_size,
                              hipStream_t stream) {
    const float* fbody   = (const float*)d_in[0];
    const float* fedge   = (const float*)d_in[1];
    const float* params  = (const float*)d_in[2];
    const float* locs    = (const float*)d_in[3];
    const float* soi     = (const float*)d_in[4];
    const int*   im_inds = (const int*)d_in[5];
    const int*   fpn     = (const int*)d_in[6];
    // d_in[7] = mask_feat_stride (always 8; factor=2 baked into the closed form)

    const int n_inst = in_sizes[5];  // 128

    dim3 grid(NSTRIPS, n_inst);
    dmh_fused8_kernel<<<grid, dim3(256), 0, stream>>>(
        fbody, fedge, params, locs, soi, im_inds, fpn,
        (float*)d_out, n_inst);
}